// Round 9
// baseline (109.010 us; speedup 1.0000x reference)
//
#include <hip/hip_runtime.h>

#define HW 16384   // 128*128

typedef __bf16 bf16x8 __attribute__((ext_vector_type(8)));
typedef __bf16 bf16x4 __attribute__((ext_vector_type(4)));
typedef float  f32x4  __attribute__((ext_vector_type(4)));
typedef float  f32x2  __attribute__((ext_vector_type(2)));

// ---------- prep: blocks<512: x -> x_t [b][pos][64] bf16 ; blocks>=512: weights ----------
__global__ __launch_bounds__(256)
void prep_all(const float* __restrict__ x, const float* __restrict__ we,
              const float* __restrict__ wc,
              __bf16* __restrict__ xt, __bf16* __restrict__ wt, __bf16* __restrict__ wcb) {
    const int t = threadIdx.x;
    if (blockIdx.x >= 512) {   // ---- weight transpose part
        int idx = (blockIdx.x - 512) * 256 + t;
        if (idx < 112 * 448) {
            int e = idx / 448, k = idx % 448;
            float v = 0.f;
            if (e < 100 && k < 432) {
                int tt = k / 48, m = k % 48;
                v = we[(e * 48 + m) * 9 + tt];
            }
            wt[idx] = (__bf16)v;
        } else {
            idx -= 112 * 448;
            if (idx < 48 * 64) wcb[idx] = (__bf16)wc[idx];
        }
        return;
    }
    // ---- x transpose part
    __shared__ float lds[256 * 65];
    const int b = blockIdx.x & 7, chunk = blockIdx.x >> 3;   // XCD-pin batch
    const int pos0 = chunk * 256;
    const float* xb = x + (size_t)b * 64 * HW + pos0;
    for (int c = 0; c < 64; ++c)
        lds[t * 65 + c] = xb[(size_t)c * HW + t];            // coalesced over t
    __syncthreads();
    const int q = t & 3, pp = t >> 2;
    #pragma unroll
    for (int it = 0; it < 4; ++it) {
        int pos = it * 64 + pp;
        __bf16* o = xt + ((size_t)b * HW + pos0 + pos) * 64 + q * 16;
        bf16x8 v0, v1;
        #pragma unroll
        for (int e = 0; e < 8; ++e) {
            v0[e] = (__bf16)lds[pos * 65 + q * 16 + e];
            v1[e] = (__bf16)lds[pos * 65 + q * 16 + 8 + e];
        }
        *(bf16x8*)o       = v0;       // wave-contiguous 2KB stores
        *(bf16x8*)(o + 8) = v1;
    }
}

// ---------- kernel W: conv1x1(MFMA) -> conv3x3(MFMA) -> softmax -> wnp f16x2 ----------
// 512 threads, tile 16x16, 512 blocks. LDS: y1[344][56] -> lgt[256][116]
__global__ __launch_bounds__(512, 4)
void carafe_weights(const __bf16* __restrict__ xt,
                    const __bf16* __restrict__ wcb, const float* __restrict__ bc,
                    const __bf16* __restrict__ wt, const float* __restrict__ be,
                    unsigned int* __restrict__ wnp) {   // [b][2][25][HW] packed f16x2
    __shared__ __align__(16) char smem[59392];
    __bf16*    y1  = (__bf16*)smem;    // [344][56]
    _Float16*  lgt = (_Float16*)smem;  // [256][116]

    const int tid = threadIdx.x;
    const int lane = tid & 63, wv = tid >> 6;
    const int lgp = lane >> 4, lr = lane & 15;
    const int b = blockIdx.x & 7, tile = blockIdx.x >> 3;    // XCD-pin batch
    const int h0 = (tile >> 3) << 4, w0 = (tile & 7) << 4;

    // ===== P1: y1[pos][m] = relu(conv1x1) via MFMA, M=336 pos, N=48, K=64
    {
        bf16x8 bw[3][2];
        float bias1[3];
        #pragma unroll
        for (int nt = 0; nt < 3; ++nt) {
            bias1[nt] = bc[nt * 16 + lr];
            #pragma unroll
            for (int kc = 0; kc < 2; ++kc)
                bw[nt][kc] = *(const bf16x8*)(wcb + (nt * 16 + lr) * 64 + kc * 32 + lgp * 8);
        }
        for (int pt = wv; pt < 21; pt += 8) {
            int pos = pt * 16 + lr;
            int pr = (pos * 1821) >> 15;  int pc = pos - pr * 18;   // /18, %18
            int hy = h0 - 1 + pr, wx = w0 - 1 + pc;
            bool ok = (hy >= 0) & (hy < 128) & (wx >= 0) & (wx < 128);
            const __bf16* ap = xt + ((size_t)b * HW + (ok ? (hy * 128 + wx) : 0)) * 64 + lgp * 8;
            bf16x8 a0 = *(const bf16x8*)ap;
            bf16x8 a1 = *(const bf16x8*)(ap + 32);
            if (!ok) {
                #pragma unroll
                for (int e = 0; e < 8; ++e) { a0[e] = (__bf16)0.f; a1[e] = (__bf16)0.f; }
            }
            #pragma unroll
            for (int nt = 0; nt < 3; ++nt) {
                f32x4 cc = {bias1[nt], bias1[nt], bias1[nt], bias1[nt]};
                cc = __builtin_amdgcn_mfma_f32_16x16x32_bf16(a0, bw[nt][0], cc, 0, 0, 0);
                cc = __builtin_amdgcn_mfma_f32_16x16x32_bf16(a1, bw[nt][1], cc, 0, 0, 0);
                #pragma unroll
                for (int r = 0; r < 4; ++r) {
                    int posw = pt * 16 + lgp * 4 + r;
                    int pr2 = (posw * 1821) >> 15;  int pc2 = posw - pr2 * 18;
                    int hy2 = h0 - 1 + pr2, wx2 = w0 - 1 + pc2;
                    bool ok2 = (hy2 >= 0) & (hy2 < 128) & (wx2 >= 0) & (wx2 < 128);
                    float v = ok2 ? fmaxf(cc[r], 0.f) : 0.f;
                    y1[posw * 56 + nt * 16 + lr] = (__bf16)v;
                }
            }
        }
    }
    if (tid < 448) y1[336 * 56 + tid] = (__bf16)0.f;   // K-pad rows (NaN*0 guard)
    __syncthreads();

    // ===== P2: logits[256px][112] = Ycol[px][432] * W[432][112], 8 waves x 2 px-tiles
    f32x4 acc[2][7];
    const int ptg0 = wv * 2;
    #pragma unroll
    for (int ot = 0; ot < 7; ++ot) {
        int o_ = ot * 16 + lr;
        float bz = (o_ < 100) ? be[o_] : 0.f;
        #pragma unroll
        for (int i = 0; i < 2; ++i) acc[i][ot] = {bz, bz, bz, bz};
    }
    {
        #pragma unroll 2
        for (int kc = 0; kc < 14; ++kc) {
            int Kb = kc * 32 + lgp * 8;
            int t  = (Kb * 683) >> 15;  int m0 = Kb - t * 48;   // k = t*48+m
            int ty = (t * 11) >> 5;     int tx = t - ty * 3;
            int base = ty * 18 + lr + tx;
            bf16x8 A[2], B[7];
            #pragma unroll
            for (int i = 0; i < 2; ++i)
                A[i] = *(const bf16x8*)(y1 + ((ptg0 + i) * 18 + base) * 56 + m0);
            #pragma unroll
            for (int j = 0; j < 7; ++j)
                B[j] = *(const bf16x8*)(wt + (j * 16 + lr) * 448 + kc * 32 + lgp * 8);
            #pragma unroll
            for (int i = 0; i < 2; ++i)
                #pragma unroll
                for (int j = 0; j < 7; ++j)
                    acc[i][j] = __builtin_amdgcn_mfma_f32_16x16x32_bf16(A[i], B[j], acc[i][j], 0, 0, 0);
        }
    }
    __syncthreads();   // y1 dead

    // ===== P3: spill logits to LDS [256][116] fp16
    #pragma unroll
    for (int i = 0; i < 2; ++i)
        #pragma unroll
        for (int j = 0; j < 7; ++j) {
            int o_ = j * 16 + lr;
            #pragma unroll
            for (int r = 0; r < 4; ++r) {
                int p = (ptg0 + i) * 16 + lgp * 4 + r;
                lgt[p * 116 + o_] = (_Float16)acc[i][j][r];
            }
        }
    __syncthreads();

    // ===== P4: softmax(25) x2 groups -> packed f16x2 store (raster order)
    const int pix = tid & 255, sgrp = tid >> 8;     // sgrp handles s-groups {2sgrp, 2sgrp+1}
    const int py = pix >> 4, px = pix & 15;
    const int h = h0 + py, w = w0 + px;
    float wt_[50];
    {
        const _Float16* lrow = lgt + pix * 116 + sgrp * 50;
        #pragma unroll
        for (int g = 0; g < 2; ++g) {
            float v[25];
            #pragma unroll
            for (int k = 0; k < 25; ++k) v[k] = (float)lrow[g * 25 + k];
            float mx = v[0];
            #pragma unroll
            for (int k = 1; k < 25; ++k) mx = fmaxf(mx, v[k]);
            float s = 0.f;
            #pragma unroll
            for (int k = 0; k < 25; ++k) { v[k] = __expf(v[k] - mx); s += v[k]; }
            float inv = 1.f / s;
            #pragma unroll
            for (int k = 0; k < 25; ++k) wt_[g * 25 + k] = v[k] * inv;
        }
    }
    unsigned int* wp = wnp + ((size_t)(b * 2 + sgrp) * 25) * HW + h * 128 + w;
    #pragma unroll
    for (int k = 0; k < 25; ++k) {
        unsigned short lo = __builtin_bit_cast(unsigned short, (_Float16)wt_[k]);
        unsigned short hi = __builtin_bit_cast(unsigned short, (_Float16)wt_[25 + k]);
        wp[(size_t)k * HW] = (unsigned int)lo | ((unsigned int)hi << 16);
    }
}

// ---------- kernel A: tile 16x8, 1024 blocks, 256 thr = 128 px x 2 group-pairs ----------
__global__ __launch_bounds__(256, 4)
void carafe_apply(const __bf16* __restrict__ xt, const unsigned int* __restrict__ wnp,
                  float* __restrict__ out) {
    __shared__ __bf16 lx[240 * 68];   // 32,640 B; rows = 20x12 halo, cols = 64 ch pad 68

    const int tid = threadIdx.x;
    const int b = blockIdx.x & 7, tile = blockIdx.x >> 3;    // XCD-pin batch
    const int tr = tile >> 4, tc = tile & 15;                // 8 x 16 tiles of 16x8
    const int h0 = tr << 4, w0 = tc << 3;

    // ---- issue halo loads (T14: keep in regs while wn loads fly)
    const int l8 = tid & 7, pg = tid >> 3;   // 32 pos-groups
    bf16x8 hv[8];
    #pragma unroll
    for (int it = 0; it < 8; ++it) {
        int pos = it * 32 + pg;
        bf16x8 v = {};
        if (pos < 240) {
            int r = pos / 12, q = pos % 12;
            int hy = h0 - 2 + r, wx = w0 - 2 + q;
            if (hy >= 0 && hy < 128 && wx >= 0 && wx < 128)
                v = *(const bf16x8*)(xt + ((size_t)b * HW + hy * 128 + wx) * 64 + l8 * 8);
        }
        hv[it] = v;
    }

    // ---- load 25 packed weight dwords (2 groups per thread)
    const int pix = tid & 127, sgrp = tid >> 7;
    const int py = pix >> 3, px8 = pix & 7;
    const int h = h0 + py, w = w0 + px8;
    float wt_[50];
    {
        const unsigned int* wp = wnp + ((size_t)(b * 2 + sgrp) * 25) * HW + h * 128 + w;
        #pragma unroll
        for (int k = 0; k < 25; ++k) {
            unsigned int u = wp[(size_t)k * HW];
            wt_[k]      = (float)__builtin_bit_cast(_Float16, (unsigned short)(u & 0xffffu));
            wt_[25 + k] = (float)__builtin_bit_cast(_Float16, (unsigned short)(u >> 16));
        }
    }

    // ---- stage halo to LDS
    #pragma unroll
    for (int it = 0; it < 8; ++it) {
        int pos = it * 32 + pg;
        if (pos < 240) {
            bf16x4 vlo = {hv[it][0], hv[it][1], hv[it][2], hv[it][3]};
            bf16x4 vhi = {hv[it][4], hv[it][5], hv[it][6], hv[it][7]};
            *(bf16x4*)(lx + pos * 68 + l8 * 8)     = vlo;
            *(bf16x4*)(lx + pos * 68 + l8 * 8 + 4) = vhi;
        }
    }
    __syncthreads();

    // ---- 5x5 weighted gather from LDS + pixel shuffle
    float* ob = out + (size_t)b * 256 * HW;
    #pragma unroll 1
    for (int cq = 0; cq < 16; ++cq) {          // channels c = 4*cq .. 4*cq+3
        f32x2 a0 = {0.f, 0.f}, a1 = {0.f, 0.f}, a2 = {0.f, 0.f}, a3 = {0.f, 0.f};
        #pragma unroll
        for (int ki = 0; ki < 5; ++ki) {
            const int rowbase = (py + ki) * 12 + px8;
            #pragma unroll
            for (int kj = 0; kj < 5; ++kj) {
                uint2 u = *(const uint2*)(lx + (rowbase + kj) * 68 + cq * 4);
                f32x2 xlo = { __uint_as_float(u.x << 16), __uint_as_float(u.x & 0xffff0000u) };
                f32x2 xhi = { __uint_as_float(u.y << 16), __uint_as_float(u.y & 0xffff0000u) };
                float wA = wt_[ki * 5 + kj];
                float wB = wt_[25 + ki * 5 + kj];
                a0 += xlo * wA;
                a1 += xhi * wA;
                a2 += xlo * wB;
                a3 += xhi * wB;
            }
        }
        // ch C = s*64 + 4cq + d -> plane q = s*16+cq, (r1,r2) = (d>>1, d&1); s = 2sgrp{+1}
        size_t base0 = ((size_t)(sgrp * 32 + cq) * 256 + 2 * h) * 256 + 2 * w;
        *(f32x2*)(ob + base0)       = a0;
        *(f32x2*)(ob + base0 + 256) = a1;
        size_t base1 = base0 + (size_t)16 * 256 * 256;
        *(f32x2*)(ob + base1)       = a2;
        *(f32x2*)(ob + base1 + 256) = a3;
    }
}

extern "C" void kernel_launch(void* const* d_in, const int* in_sizes, int n_in,
                              void* d_out, int out_size, void* d_ws, size_t ws_size,
                              hipStream_t stream) {
    const float* x  = (const float*)d_in[0];   // [8][64][128][128]
    const float* wc = (const float*)d_in[1];   // [48][64]
    const float* bc = (const float*)d_in[2];   // [48]
    const float* we = (const float*)d_in[3];   // [100][48][3][3]
    const float* be = (const float*)d_in[4];   // [100]
    float* out = (float*)d_out;                // [8][64][256][256]

    // ws: xt 16,777,216 | w_t 100,352 | wc_bf 6,144 | wnp 26,214,400  (~43.1 MB)
    __bf16*       xt  = (__bf16*)d_ws;
    __bf16*       wte = (__bf16*)((char*)d_ws + 16777216);
    __bf16*       wcb = (__bf16*)((char*)d_ws + 16777216 + 100352);
    unsigned int* wnp = (unsigned int*)((char*)d_ws + 16883712);

    prep_all<<<512 + 208, 256, 0, stream>>>(x, we, wc, xt, wte, wcb);
    carafe_weights<<<512, 512, 0, stream>>>(xt, wcb, bc, wte, be, wnp);
    carafe_apply<<<1024, 256, 0, stream>>>(xt, wnp, out);
}

// Round 10
// 108.098 us; speedup vs baseline: 1.0084x; 1.0084x over previous
//
#include <hip/hip_runtime.h>

#define HW 16384   // 128*128

typedef __bf16 bf16x8 __attribute__((ext_vector_type(8)));
typedef __bf16 bf16x4 __attribute__((ext_vector_type(4)));
typedef float  f32x4  __attribute__((ext_vector_type(4)));
typedef float  f32x2  __attribute__((ext_vector_type(2)));

// ---------- prep: blocks<512: x -> x_t [b][pos][64] bf16 ; blocks>=512: weights ----------
__global__ __launch_bounds__(256)
void prep_all(const float* __restrict__ x, const float* __restrict__ we,
              const float* __restrict__ wc,
              __bf16* __restrict__ xt, __bf16* __restrict__ wt, __bf16* __restrict__ wcb) {
    const int t = threadIdx.x;
    if (blockIdx.x >= 512) {   // ---- weight transpose part
        int idx = (blockIdx.x - 512) * 256 + t;
        if (idx < 112 * 448) {
            int e = idx / 448, k = idx % 448;
            float v = 0.f;
            if (e < 100 && k < 432) {
                int tt = k / 48, m = k % 48;
                v = we[(e * 48 + m) * 9 + tt];
            }
            wt[idx] = (__bf16)v;
        } else {
            idx -= 112 * 448;
            if (idx < 48 * 64) wcb[idx] = (__bf16)wc[idx];
        }
        return;
    }
    // ---- x transpose part
    __shared__ float lds[256 * 65];
    const int b = blockIdx.x & 7, chunk = blockIdx.x >> 3;   // XCD-pin batch
    const int pos0 = chunk * 256;
    const float* xb = x + (size_t)b * 64 * HW + pos0;
    for (int c = 0; c < 64; ++c)
        lds[t * 65 + c] = xb[(size_t)c * HW + t];            // coalesced over t
    __syncthreads();
    const int q = t & 3, pp = t >> 2;
    #pragma unroll
    for (int it = 0; it < 4; ++it) {
        int pos = it * 64 + pp;
        __bf16* o = xt + ((size_t)b * HW + pos0 + pos) * 64 + q * 16;
        bf16x8 v0, v1;
        #pragma unroll
        for (int e = 0; e < 8; ++e) {
            v0[e] = (__bf16)lds[pos * 65 + q * 16 + e];
            v1[e] = (__bf16)lds[pos * 65 + q * 16 + 8 + e];
        }
        *(bf16x8*)o       = v0;       // wave-contiguous 2KB stores
        *(bf16x8*)(o + 8) = v1;
    }
}

// ---------- kernel W: conv1x1(MFMA) -> conv3x3(MFMA) -> softmax -> packed f16x2 ----------
// 512 threads, tile 16x16, 512 blocks (2/CU). LDS: y1[344][56] -> lgt[256][118]
__global__ __launch_bounds__(512, 4)
void carafe_weights(const __bf16* __restrict__ xt,
                    const __bf16* __restrict__ wcb, const float* __restrict__ bc,
                    const __bf16* __restrict__ wt, const float* __restrict__ be,
                    unsigned int* __restrict__ wnp) {   // [(b*2+sgrp)*25+k][tile*256+pix]
    __shared__ __align__(16) char smem[60416];
    __bf16*    y1  = (__bf16*)smem;    // [344][56]
    _Float16*  lgt = (_Float16*)smem;  // [256][118]  (stride 118: odd dword -> no conflicts)

    const int tid = threadIdx.x;
    const int lane = tid & 63, wv = tid >> 6;
    const int lgp = lane >> 4, lr = lane & 15;
    const int b = blockIdx.x & 7, tile = blockIdx.x >> 3;    // XCD-pin batch
    const int h0 = (tile >> 3) << 4, w0 = (tile & 7) << 4;

    // ===== P1: y1[pos][m] = relu(conv1x1) via MFMA, M=336 pos, N=48, K=64
    {
        bf16x8 bw[3][2];
        float bias1[3];
        #pragma unroll
        for (int nt = 0; nt < 3; ++nt) {
            bias1[nt] = bc[nt * 16 + lr];
            #pragma unroll
            for (int kc = 0; kc < 2; ++kc)
                bw[nt][kc] = *(const bf16x8*)(wcb + (nt * 16 + lr) * 64 + kc * 32 + lgp * 8);
        }
        for (int pt = wv; pt < 21; pt += 8) {
            int pos = pt * 16 + lr;
            int pr = (pos * 1821) >> 15;  int pc = pos - pr * 18;   // /18, %18
            int hy = h0 - 1 + pr, wx = w0 - 1 + pc;
            bool ok = (hy >= 0) & (hy < 128) & (wx >= 0) & (wx < 128);
            const __bf16* ap = xt + ((size_t)b * HW + (ok ? (hy * 128 + wx) : 0)) * 64 + lgp * 8;
            bf16x8 a0 = *(const bf16x8*)ap;
            bf16x8 a1 = *(const bf16x8*)(ap + 32);
            if (!ok) {
                #pragma unroll
                for (int e = 0; e < 8; ++e) { a0[e] = (__bf16)0.f; a1[e] = (__bf16)0.f; }
            }
            #pragma unroll
            for (int nt = 0; nt < 3; ++nt) {
                f32x4 cc = {bias1[nt], bias1[nt], bias1[nt], bias1[nt]};
                cc = __builtin_amdgcn_mfma_f32_16x16x32_bf16(a0, bw[nt][0], cc, 0, 0, 0);
                cc = __builtin_amdgcn_mfma_f32_16x16x32_bf16(a1, bw[nt][1], cc, 0, 0, 0);
                #pragma unroll
                for (int r = 0; r < 4; ++r) {
                    int posw = pt * 16 + lgp * 4 + r;
                    int pr2 = (posw * 1821) >> 15;  int pc2 = posw - pr2 * 18;
                    int hy2 = h0 - 1 + pr2, wx2 = w0 - 1 + pc2;
                    bool ok2 = (hy2 >= 0) & (hy2 < 128) & (wx2 >= 0) & (wx2 < 128);
                    float v = ok2 ? fmaxf(cc[r], 0.f) : 0.f;
                    y1[posw * 56 + nt * 16 + lr] = (__bf16)v;
                }
            }
        }
    }
    if (tid < 448) y1[336 * 56 + tid] = (__bf16)0.f;   // K-pad rows (NaN*0 guard)
    __syncthreads();

    // ===== P2: logits[256px][112] = Ycol[px][432] * W[432][112], 8 waves x 2 px-tiles
    f32x4 acc[2][7];
    const int ptg0 = wv * 2;
    #pragma unroll
    for (int ot = 0; ot < 7; ++ot) {
        int o_ = ot * 16 + lr;
        float bz = (o_ < 100) ? be[o_] : 0.f;
        #pragma unroll
        for (int i = 0; i < 2; ++i) acc[i][ot] = {bz, bz, bz, bz};
    }
    {
        #pragma unroll 2
        for (int kc = 0; kc < 14; ++kc) {
            int Kb = kc * 32 + lgp * 8;
            int t  = (Kb * 683) >> 15;  int m0 = Kb - t * 48;   // k = t*48+m
            int ty = (t * 11) >> 5;     int tx = t - ty * 3;
            int base = ty * 18 + lr + tx;
            bf16x8 A[2], B[7];
            #pragma unroll
            for (int i = 0; i < 2; ++i)
                A[i] = *(const bf16x8*)(y1 + ((ptg0 + i) * 18 + base) * 56 + m0);
            #pragma unroll
            for (int j = 0; j < 7; ++j)
                B[j] = *(const bf16x8*)(wt + (j * 16 + lr) * 448 + kc * 32 + lgp * 8);
            #pragma unroll
            for (int i = 0; i < 2; ++i)
                #pragma unroll
                for (int j = 0; j < 7; ++j)
                    acc[i][j] = __builtin_amdgcn_mfma_f32_16x16x32_bf16(A[i], B[j], acc[i][j], 0, 0, 0);
        }
    }
    __syncthreads();   // y1 dead

    // ===== P3: spill logits to LDS [256][118] fp16
    #pragma unroll
    for (int i = 0; i < 2; ++i)
        #pragma unroll
        for (int j = 0; j < 7; ++j) {
            int o_ = j * 16 + lr;
            #pragma unroll
            for (int r = 0; r < 4; ++r) {
                int p = (ptg0 + i) * 16 + lgp * 4 + r;
                lgt[p * 118 + o_] = (_Float16)acc[i][j][r];
            }
        }
    __syncthreads();

    // ===== P4: softmax(25) x2 groups -> packed f16x2, tile-local contiguous store
    const int pix = tid & 255, sgrp = tid >> 8;     // sgrp: groups {2sgrp, 2sgrp+1}
    float wt_[50];
    {
        const _Float16* lrow = lgt + pix * 118 + sgrp * 50;
        #pragma unroll
        for (int g = 0; g < 2; ++g) {
            float v[25];
            #pragma unroll
            for (int k = 0; k < 25; ++k) v[k] = (float)lrow[g * 25 + k];
            float mx = v[0];
            #pragma unroll
            for (int k = 1; k < 25; ++k) mx = fmaxf(mx, v[k]);
            float s = 0.f;
            #pragma unroll
            for (int k = 0; k < 25; ++k) { v[k] = __expf(v[k] - mx); s += v[k]; }
            float inv = 1.f / s;
            #pragma unroll
            for (int k = 0; k < 25; ++k) wt_[g * 25 + k] = v[k] * inv;
        }
    }
    unsigned int* wp = wnp + (size_t)(b * 2 + sgrp) * 25 * HW + tile * 256 + pix;
    #pragma unroll
    for (int k = 0; k < 25; ++k) {
        unsigned short lo = __builtin_bit_cast(unsigned short, (_Float16)wt_[k]);
        unsigned short hi = __builtin_bit_cast(unsigned short, (_Float16)wt_[25 + k]);
        wp[(size_t)k * HW] = (unsigned int)lo | ((unsigned int)hi << 16);   // 256B/wave contiguous
    }
}

// ---------- kernel A: tile 16x16, 512 blocks, 512 thr = 256 px x 2 group-pairs ----------
__global__ __launch_bounds__(512, 4)
void carafe_apply(const __bf16* __restrict__ xt, const unsigned int* __restrict__ wnp,
                  float* __restrict__ out) {
    __shared__ __bf16 lx[400 * 68];   // 54,400 B; rows = 20x20 halo, cols = 64 ch pad 68

    const int tid = threadIdx.x;
    const int b = blockIdx.x & 7, tile = blockIdx.x >> 3;    // XCD-pin batch
    const int h0 = (tile >> 3) << 4, w0 = (tile & 7) << 4;

    // ---- T14 issue: halo loads into regs (fly over the weight loads)
    const int l8 = tid & 7, pg = tid >> 3;   // 64 pos-groups
    bf16x8 hv[7];
    #pragma unroll
    for (int it = 0; it < 7; ++it) {
        int pos = it * 64 + pg;
        bf16x8 v = {};
        if (pos < 400) {
            int r = pos / 20, q = pos % 20;
            int hy = h0 - 2 + r, wx = w0 - 2 + q;
            if (hy >= 0 && hy < 128 && wx >= 0 && wx < 128)
                v = *(const bf16x8*)(xt + ((size_t)b * HW + hy * 128 + wx) * 64 + l8 * 8);
        }
        hv[it] = v;
    }

    // ---- load 25 packed weight dwords (2 groups per thread), contiguous per wave
    const int pix = tid & 255, sgrp = tid >> 8;
    const int py = pix >> 4, px = pix & 15;
    const int h = h0 + py, w = w0 + px;
    float wt_[50];
    {
        const unsigned int* wp = wnp + (size_t)(b * 2 + sgrp) * 25 * HW + tile * 256 + pix;
        #pragma unroll
        for (int k = 0; k < 25; ++k) {
            unsigned int u = wp[(size_t)k * HW];
            wt_[k]      = (float)__builtin_bit_cast(_Float16, (unsigned short)(u & 0xffffu));
            wt_[25 + k] = (float)__builtin_bit_cast(_Float16, (unsigned short)(u >> 16));
        }
    }

    // ---- T14 write: stage halo to LDS
    #pragma unroll
    for (int it = 0; it < 7; ++it) {
        int pos = it * 64 + pg;
        if (pos < 400) {
            bf16x4 vlo = {hv[it][0], hv[it][1], hv[it][2], hv[it][3]};
            bf16x4 vhi = {hv[it][4], hv[it][5], hv[it][6], hv[it][7]};
            *(bf16x4*)(lx + pos * 68 + l8 * 8)     = vlo;
            *(bf16x4*)(lx + pos * 68 + l8 * 8 + 4) = vhi;
        }
    }
    __syncthreads();

    // ---- 5x5 weighted gather from LDS + pixel shuffle
    float* ob = out + (size_t)b * 256 * HW;
    #pragma unroll 1
    for (int cq = 0; cq < 16; ++cq) {          // channels c = 4*cq .. 4*cq+3
        f32x2 a0 = {0.f, 0.f}, a1 = {0.f, 0.f}, a2 = {0.f, 0.f}, a3 = {0.f, 0.f};
        #pragma unroll
        for (int ki = 0; ki < 5; ++ki) {
            const int rowbase = (py + ki) * 20 + px;
            #pragma unroll
            for (int kj = 0; kj < 5; ++kj) {
                uint2 u = *(const uint2*)(lx + (rowbase + kj) * 68 + cq * 4);
                f32x2 xlo = { __uint_as_float(u.x << 16), __uint_as_float(u.x & 0xffff0000u) };
                f32x2 xhi = { __uint_as_float(u.y << 16), __uint_as_float(u.y & 0xffff0000u) };
                float wA = wt_[ki * 5 + kj];
                float wB = wt_[25 + ki * 5 + kj];
                a0 += xlo * wA;
                a1 += xhi * wA;
                a2 += xlo * wB;
                a3 += xhi * wB;
            }
        }
        // ch C = s*64 + 4cq + d -> plane q = s*16+cq, (r1,r2) = (d>>1, d&1); s = 2sgrp{+1}
        size_t base0 = ((size_t)(sgrp * 32 + cq) * 256 + 2 * h) * 256 + 2 * w;
        *(f32x2*)(ob + base0)       = a0;
        *(f32x2*)(ob + base0 + 256) = a1;
        size_t base1 = base0 + (size_t)16 * 256 * 256;
        *(f32x2*)(ob + base1)       = a2;
        *(f32x2*)(ob + base1 + 256) = a3;
    }
}

extern "C" void kernel_launch(void* const* d_in, const int* in_sizes, int n_in,
                              void* d_out, int out_size, void* d_ws, size_t ws_size,
                              hipStream_t stream) {
    const float* x  = (const float*)d_in[0];   // [8][64][128][128]
    const float* wc = (const float*)d_in[1];   // [48][64]
    const float* bc = (const float*)d_in[2];   // [48]
    const float* we = (const float*)d_in[3];   // [100][48][3][3]
    const float* be = (const float*)d_in[4];   // [100]
    float* out = (float*)d_out;                // [8][64][256][256]

    // ws: xt 16,777,216 | w_t 100,352 | wc_bf 6,144 | wnp 26,214,400  (~43.1 MB)
    __bf16*       xt  = (__bf16*)d_ws;
    __bf16*       wte = (__bf16*)((char*)d_ws + 16777216);
    __bf16*       wcb = (__bf16*)((char*)d_ws + 16777216 + 100352);
    unsigned int* wnp = (unsigned int*)((char*)d_ws + 16883712);

    prep_all<<<512 + 208, 256, 0, stream>>>(x, we, wc, xt, wte, wcb);
    carafe_weights<<<512, 512, 0, stream>>>(xt, wcb, bc, wte, be, wnp);
    carafe_apply<<<512, 512, 0, stream>>>(xt, wnp, out);
}

// Round 11
// 92.335 us; speedup vs baseline: 1.1806x; 1.1707x over previous
//
#include <hip/hip_runtime.h>

#define HW 16384   // 128*128

typedef __bf16 bf16x8 __attribute__((ext_vector_type(8)));
typedef __bf16 bf16x4 __attribute__((ext_vector_type(4)));
typedef float  f32x4  __attribute__((ext_vector_type(4)));
typedef float  f32x2  __attribute__((ext_vector_type(2)));

// ---------- prep 1: x [b][64][128][128] f32 -> x_t [b][pos][64] bf16 ----------
__global__ __launch_bounds__(256)
void prep_xt(const float* __restrict__ x, __bf16* __restrict__ xt) {
    __shared__ float lds[256 * 65];
    const int b = blockIdx.x & 7, chunk = blockIdx.x >> 3;   // XCD-pin batch
    const int t = threadIdx.x;
    const int pos0 = chunk * 256;
    const float* xb = x + (size_t)b * 64 * HW + pos0;
    for (int c = 0; c < 64; ++c)
        lds[t * 65 + c] = xb[(size_t)c * HW + t];            // coalesced over t
    __syncthreads();
    const int q = t & 3, pp = t >> 2;
    #pragma unroll
    for (int it = 0; it < 4; ++it) {
        int pos = it * 64 + pp;
        __bf16* o = xt + ((size_t)b * HW + pos0 + pos) * 64 + q * 16;
        bf16x8 v0, v1;
        #pragma unroll
        for (int e = 0; e < 8; ++e) {
            v0[e] = (__bf16)lds[pos * 65 + q * 16 + e];
            v1[e] = (__bf16)lds[pos * 65 + q * 16 + 8 + e];
        }
        *(bf16x8*)o       = v0;       // wave-contiguous 2KB stores
        *(bf16x8*)(o + 8) = v1;
    }
}

// ---------- prep 2: w_t[112][448] bf16 (k = t*48+m), wc_bf[48][64] bf16 ----------
__global__ __launch_bounds__(256)
void prep_w(const float* __restrict__ we, const float* __restrict__ wc,
            __bf16* __restrict__ wt, __bf16* __restrict__ wcb) {
    int idx = blockIdx.x * 256 + threadIdx.x;
    if (idx < 112 * 448) {
        int e = idx / 448, k = idx % 448;
        float v = 0.f;
        if (e < 100 && k < 432) {
            int t = k / 48, m = k % 48;
            v = we[(e * 48 + m) * 9 + t];
        }
        wt[idx] = (__bf16)v;
    } else {
        idx -= 112 * 448;
        if (idx < 48 * 64) wcb[idx] = (__bf16)wc[idx];
    }
}

// ---------- kernel W: conv1x1(MFMA) -> conv3x3(MFMA) -> softmax -> packed f16x2 ----------
// 256 threads, tile 16x16, 512 blocks (2/CU). LDS: y1[344][56] -> lgt[256][116]
__global__ __launch_bounds__(256, 2)
void carafe_weights(const __bf16* __restrict__ xt,
                    const __bf16* __restrict__ wcb, const float* __restrict__ bc,
                    const __bf16* __restrict__ wt, const float* __restrict__ be,
                    unsigned int* __restrict__ wnp) {   // [(b*2+s2)*25+k][tile*256+pix]
    __shared__ __align__(16) char smem[59392];
    __bf16*    y1  = (__bf16*)smem;    // [344][56]
    _Float16*  lgt = (_Float16*)smem;  // [256][116]

    const int tid = threadIdx.x;
    const int lane = tid & 63, wv = tid >> 6;
    const int lgp = lane >> 4, lr = lane & 15;
    const int b = blockIdx.x & 7, tile = blockIdx.x >> 3;    // XCD-pin batch
    const int h0 = (tile >> 3) << 4, w0 = (tile & 7) << 4;

    // ===== P1: y1[pos][m] = relu(conv1x1) via MFMA, M=336 pos, N=48, K=64
    {
        bf16x8 bw[3][2];
        float bias1[3];
        #pragma unroll
        for (int nt = 0; nt < 3; ++nt) {
            bias1[nt] = bc[nt * 16 + lr];
            #pragma unroll
            for (int kc = 0; kc < 2; ++kc)
                bw[nt][kc] = *(const bf16x8*)(wcb + (nt * 16 + lr) * 64 + kc * 32 + lgp * 8);
        }
        for (int pt = wv; pt < 21; pt += 4) {
            int pos = pt * 16 + lr;
            int pr = (pos * 1821) >> 15;  int pc = pos - pr * 18;   // /18, %18
            int hy = h0 - 1 + pr, wx = w0 - 1 + pc;
            bool ok = (hy >= 0) & (hy < 128) & (wx >= 0) & (wx < 128);
            const __bf16* ap = xt + ((size_t)b * HW + (ok ? (hy * 128 + wx) : 0)) * 64 + lgp * 8;
            bf16x8 a0 = *(const bf16x8*)ap;
            bf16x8 a1 = *(const bf16x8*)(ap + 32);
            if (!ok) {
                #pragma unroll
                for (int e = 0; e < 8; ++e) { a0[e] = (__bf16)0.f; a1[e] = (__bf16)0.f; }
            }
            #pragma unroll
            for (int nt = 0; nt < 3; ++nt) {
                f32x4 cc = {bias1[nt], bias1[nt], bias1[nt], bias1[nt]};
                cc = __builtin_amdgcn_mfma_f32_16x16x32_bf16(a0, bw[nt][0], cc, 0, 0, 0);
                cc = __builtin_amdgcn_mfma_f32_16x16x32_bf16(a1, bw[nt][1], cc, 0, 0, 0);
                #pragma unroll
                for (int r = 0; r < 4; ++r) {
                    int posw = pt * 16 + lgp * 4 + r;
                    int pr2 = (posw * 1821) >> 15;  int pc2 = posw - pr2 * 18;
                    int hy2 = h0 - 1 + pr2, wx2 = w0 - 1 + pc2;
                    bool ok2 = (hy2 >= 0) & (hy2 < 128) & (wx2 >= 0) & (wx2 < 128);
                    float v = ok2 ? fmaxf(cc[r], 0.f) : 0.f;
                    y1[posw * 56 + nt * 16 + lr] = (__bf16)v;
                }
            }
        }
    }
    for (int i = tid; i < 448; i += 256)
        y1[336 * 56 + i] = (__bf16)0.f;          // K-pad rows (NaN*0 guard)
    __syncthreads();

    // ===== P2: logits[256px][112] = Ycol[px][432] * W[432][112], 4 waves x 4 px-tiles
    f32x4 acc[4][7];
    #pragma unroll
    for (int ot = 0; ot < 7; ++ot) {
        int o_ = ot * 16 + lr;
        float bz = (o_ < 100) ? be[o_] : 0.f;
        #pragma unroll
        for (int i = 0; i < 4; ++i) acc[i][ot] = {bz, bz, bz, bz};
    }
    const int ptg0 = wv * 4;

    auto ldA = [&](bf16x8 A[4], int kc) {
        int Kb = kc * 32 + lgp * 8;
        int t  = (Kb * 683) >> 15;  int m0 = Kb - t * 48;   // k = t*48+m
        int ty = (t * 11) >> 5;     int tx = t - ty * 3;
        int base = ty * 18 + lr + tx;
        #pragma unroll
        for (int i = 0; i < 4; ++i)
            A[i] = *(const bf16x8*)(y1 + ((ptg0 + i) * 18 + base) * 56 + m0);
    };
    auto ldB = [&](bf16x8 B[7], int kc) {
        #pragma unroll
        for (int j = 0; j < 7; ++j)
            B[j] = *(const bf16x8*)(wt + (j * 16 + lr) * 448 + kc * 32 + lgp * 8);
    };
    auto mm = [&](bf16x8 A[4], bf16x8 B[7]) {
        #pragma unroll
        for (int i = 0; i < 4; ++i)
            #pragma unroll
            for (int j = 0; j < 7; ++j)
                acc[i][j] = __builtin_amdgcn_mfma_f32_16x16x32_bf16(A[i], B[j], acc[i][j], 0, 0, 0);
    };

    bf16x8 A0[4], B0[7], A1[4], B1[7];
    ldA(A0, 0); ldB(B0, 0);
    #pragma unroll
    for (int kc = 0; kc < 14; kc += 2) {
        if (kc + 1 < 14) { ldA(A1, kc + 1); ldB(B1, kc + 1); }
        mm(A0, B0);
        if (kc + 2 < 14) { ldA(A0, kc + 2); ldB(B0, kc + 2); }
        if (kc + 1 < 14) mm(A1, B1);
    }
    __syncthreads();   // y1 dead

    // ===== P3: spill logits to LDS [256][116] fp16
    #pragma unroll
    for (int i = 0; i < 4; ++i)
        #pragma unroll
        for (int j = 0; j < 7; ++j) {
            int o_ = j * 16 + lr;
            #pragma unroll
            for (int r = 0; r < 4; ++r) {
                int p = (ptg0 + i) * 16 + lgp * 4 + r;
                lgt[p * 116 + o_] = (_Float16)acc[i][j][r];
            }
        }
    __syncthreads();

    // ===== P4: per-pixel softmax(25) x4 groups -> packed f16x2 tile-local store
    const int p = tid;
    float wt_[100];
    const _Float16* lrow = lgt + p * 116;
    #pragma unroll
    for (int g = 0; g < 4; ++g) {
        float v[25];
        #pragma unroll
        for (int k = 0; k < 25; ++k) v[k] = (float)lrow[g * 25 + k];
        float mx = v[0];
        #pragma unroll
        for (int k = 1; k < 25; ++k) mx = fmaxf(mx, v[k]);
        float s = 0.f;
        #pragma unroll
        for (int k = 0; k < 25; ++k) { v[k] = __expf(v[k] - mx); s += v[k]; }
        float inv = 1.f / s;
        #pragma unroll
        for (int k = 0; k < 25; ++k) wt_[g * 25 + k] = v[k] * inv;
    }
    #pragma unroll
    for (int s2 = 0; s2 < 2; ++s2) {
        unsigned int* wp = wnp + (size_t)(b * 2 + s2) * 25 * HW + tile * 256 + p;
        #pragma unroll
        for (int k = 0; k < 25; ++k) {
            unsigned short lo = __builtin_bit_cast(unsigned short, (_Float16)wt_[s2 * 50 + k]);
            unsigned short hi = __builtin_bit_cast(unsigned short, (_Float16)wt_[s2 * 50 + 25 + k]);
            wp[(size_t)k * HW] = (unsigned int)lo | ((unsigned int)hi << 16);  // 256B/wave
        }
    }
}

// ---------- kernel A: tile 16x16, 512 blocks, 512 thr = 256 px x 2 group-pairs ----------
__global__ __launch_bounds__(512, 4)
void carafe_apply(const __bf16* __restrict__ xt, const unsigned int* __restrict__ wnp,
                  float* __restrict__ out) {
    __shared__ __bf16 lx[400 * 68];   // 54,400 B; rows = 20x20 halo, cols = 64 ch pad 68

    const int tid = threadIdx.x;
    const int b = blockIdx.x & 7, tile = blockIdx.x >> 3;    // XCD-pin batch
    const int h0 = (tile >> 3) << 4, w0 = (tile & 7) << 4;

    // ---- T14 issue: halo loads into regs (fly over the weight loads)
    const int l8 = tid & 7, pg = tid >> 3;   // 64 pos-groups
    bf16x8 hv[7];
    #pragma unroll
    for (int it = 0; it < 7; ++it) {
        int pos = it * 64 + pg;
        bf16x8 v = {};
        if (pos < 400) {
            int r = pos / 20, q = pos % 20;
            int hy = h0 - 2 + r, wx = w0 - 2 + q;
            if (hy >= 0 && hy < 128 && wx >= 0 && wx < 128)
                v = *(const bf16x8*)(xt + ((size_t)b * HW + hy * 128 + wx) * 64 + l8 * 8);
        }
        hv[it] = v;
    }

    // ---- load 25 packed weight dwords (2 groups per thread), contiguous per wave
    const int pix = tid & 255, sgrp = tid >> 8;
    const int py = pix >> 4, px = pix & 15;
    const int h = h0 + py, w = w0 + px;
    float wt_[50];
    {
        const unsigned int* wp = wnp + (size_t)(b * 2 + sgrp) * 25 * HW + tile * 256 + pix;
        #pragma unroll
        for (int k = 0; k < 25; ++k) {
            unsigned int u = wp[(size_t)k * HW];
            wt_[k]      = (float)__builtin_bit_cast(_Float16, (unsigned short)(u & 0xffffu));
            wt_[25 + k] = (float)__builtin_bit_cast(_Float16, (unsigned short)(u >> 16));
        }
    }

    // ---- T14 write: stage halo to LDS
    #pragma unroll
    for (int it = 0; it < 7; ++it) {
        int pos = it * 64 + pg;
        if (pos < 400) {
            bf16x4 vlo = {hv[it][0], hv[it][1], hv[it][2], hv[it][3]};
            bf16x4 vhi = {hv[it][4], hv[it][5], hv[it][6], hv[it][7]};
            *(bf16x4*)(lx + pos * 68 + l8 * 8)     = vlo;
            *(bf16x4*)(lx + pos * 68 + l8 * 8 + 4) = vhi;
        }
    }
    __syncthreads();

    // ---- 5x5 weighted gather from LDS + pixel shuffle
    float* ob = out + (size_t)b * 256 * HW;
    #pragma unroll 1
    for (int cq = 0; cq < 16; ++cq) {          // channels c = 4*cq .. 4*cq+3
        f32x2 a0 = {0.f, 0.f}, a1 = {0.f, 0.f}, a2 = {0.f, 0.f}, a3 = {0.f, 0.f};
        #pragma unroll
        for (int ki = 0; ki < 5; ++ki) {
            const int rowbase = (py + ki) * 20 + px;
            #pragma unroll
            for (int kj = 0; kj < 5; ++kj) {
                uint2 u = *(const uint2*)(lx + (rowbase + kj) * 68 + cq * 4);
                f32x2 xlo = { __uint_as_float(u.x << 16), __uint_as_float(u.x & 0xffff0000u) };
                f32x2 xhi = { __uint_as_float(u.y << 16), __uint_as_float(u.y & 0xffff0000u) };
                float wA = wt_[ki * 5 + kj];
                float wB = wt_[25 + ki * 5 + kj];
                a0 += xlo * wA;
                a1 += xhi * wA;
                a2 += xlo * wB;
                a3 += xhi * wB;
            }
        }
        // ch C = s*64 + 4cq + d -> plane q = s*16+cq, (r1,r2) = (d>>1, d&1); s = 2sgrp{+1}
        size_t base0 = ((size_t)(sgrp * 32 + cq) * 256 + 2 * h) * 256 + 2 * w;
        *(f32x2*)(ob + base0)       = a0;
        *(f32x2*)(ob + base0 + 256) = a1;
        size_t base1 = base0 + (size_t)16 * 256 * 256;
        *(f32x2*)(ob + base1)       = a2;
        *(f32x2*)(ob + base1 + 256) = a3;
    }
}

extern "C" void kernel_launch(void* const* d_in, const int* in_sizes, int n_in,
                              void* d_out, int out_size, void* d_ws, size_t ws_size,
                              hipStream_t stream) {
    const float* x  = (const float*)d_in[0];   // [8][64][128][128]
    const float* wc = (const float*)d_in[1];   // [48][64]
    const float* bc = (const float*)d_in[2];   // [48]
    const float* we = (const float*)d_in[3];   // [100][48][3][3]
    const float* be = (const float*)d_in[4];   // [100]
    float* out = (float*)d_out;                // [8][64][256][256]

    // ws: xt 16,777,216 | w_t 100,352 | wc_bf 6,144 | wnp 26,214,400  (~43.1 MB)
    __bf16*       xt  = (__bf16*)d_ws;
    __bf16*       wte = (__bf16*)((char*)d_ws + 16777216);
    __bf16*       wcb = (__bf16*)((char*)d_ws + 16777216 + 100352);
    unsigned int* wnp = (unsigned int*)((char*)d_ws + 16883712);

    prep_xt<<<512, 256, 0, stream>>>(x, xt);
    prep_w<<<208, 256, 0, stream>>>(we, wc, wte, wcb);
    carafe_weights<<<512, 256, 0, stream>>>(xt, wcb, bc, wte, be, wnp);
    carafe_apply<<<512, 512, 0, stream>>>(xt, wnp, out);
}